// Round 8
// baseline (315.851 us; speedup 1.0000x reference)
//
#include <hip/hip_runtime.h>

#define EMB 64
#define HEADS 2
#define NUM_BOND 5
#define NEG_SLOPE 0.2f

__device__ __forceinline__ unsigned bf16rne(float f){
    unsigned u = __float_as_uint(f);
    return (u + 0x7FFFu + ((u >> 16) & 1u)) >> 16;
}
__device__ __forceinline__ float bf16lo(unsigned p){ return __uint_as_float(p << 16); }
__device__ __forceinline__ float bf16hi(unsigned p){ return __uint_as_float(p & 0xFFFF0000u); }

// fused: consts (block 0) + src histogram + node transform.
// hb = packed bf16 {head0|head1<<16}; a_i, a_jn stored RAW.
__global__ __launch_bounds__(256) void k_node(const float* __restrict__ x,
        const float* __restrict__ W_lin, const float* __restrict__ b_lin,
        const float* __restrict__ att,
        const float* __restrict__ W_edge, const float* __restrict__ b_edge,
        const int* __restrict__ ei, int E,
        unsigned* __restrict__ hb, float* __restrict__ a_i, float* __restrict__ a_jn,
        float* __restrict__ consts, int* __restrict__ cnt, int N){
    __shared__ float WL[EMB*HEADS*EMB];          // 32 KB
    int t = threadIdx.x;
    if (blockIdx.x == 0 && t < 12){              // consts[2b+h], consts[10+h]
        int h = t & 1;
        const float* aj = att + h*2*EMB + EMB;
        float s = 0.f;
        if (t < 10){
            int b = t >> 1;
            for (int c = 0; c < EMB; c++) s += W_edge[b*(HEADS*EMB) + h*EMB + c] * aj[c];
        } else {
            for (int c = 0; c < EMB; c++) s += b_edge[h*EMB + c] * aj[c];
        }
        consts[t] = s;
    }
    for (int e = blockIdx.x*256 + t; e < E; e += gridDim.x*256)
        atomicAdd(cnt + ei[e], 1);
    for (int i = t; i < EMB*HEADS*EMB; i += 256) WL[i] = W_lin[i];
    __syncthreads();
    int wid = t >> 6, lane = t & 63;
    for (int n = blockIdx.x*4 + wid; n < N; n += gridDim.x*4){
        float xv = x[(size_t)n*EMB + lane];
        float acc0 = b_lin[lane], acc1 = b_lin[64 + lane];
        #pragma unroll 8
        for (int k = 0; k < EMB; k++){
            float xk = __shfl(xv, k);
            acc0 += xk * WL[k*128 + lane];
            acc1 += xk * WL[k*128 + 64 + lane];
        }
        hb[(size_t)n*EMB + lane] = bf16rne(acc0) | (bf16rne(acc1) << 16);
        float p0 = acc0 * att[lane];
        float p1 = acc1 * att[128 + lane];
        float q0 = acc0 * att[64 + lane];
        float q1 = acc1 * att[192 + lane];
        for (int off = 32; off; off >>= 1){
            p0 += __shfl_xor(p0, off);
            p1 += __shfl_xor(p1, off);
            q0 += __shfl_xor(q0, off);
            q1 += __shfl_xor(q1, off);
        }
        if (lane == 0){
            a_i[n*2]  = p0; a_i[n*2+1]  = p1;
            a_jn[n*2] = q0; a_jn[n*2+1] = q1;
        }
    }
}

// hierarchical scan, stage 1: per-block (1024) exclusive scan + block sums
__global__ __launch_bounds__(1024) void k_scan1(const int* __restrict__ cnt,
        int* __restrict__ loc, int* __restrict__ bsum, int N){
    __shared__ int wsum[16];
    int t = threadIdx.x, lane = t & 63, wid = t >> 6;
    int i = blockIdx.x*1024 + t;
    int v = (i < N) ? cnt[i] : 0;
    int s = v;
    #pragma unroll
    for (int off = 1; off < 64; off <<= 1){
        int u = __shfl_up(s, off);
        if (lane >= off) s += u;
    }
    if (lane == 63) wsum[wid] = s;
    __syncthreads();
    if (t < 16){
        int w = wsum[t];
        #pragma unroll
        for (int off = 1; off < 16; off <<= 1){
            int u = __shfl_up(w, off);
            if (t >= off) w += u;
        }
        wsum[t] = w;
    }
    __syncthreads();
    int excl = (s - v) + (wid ? wsum[wid - 1] : 0);
    if (i < N) loc[i] = excl;
    if (t == 1023) bsum[blockIdx.x] = excl + v;
}

// stage 2: single wave exclusive-scans the (<=64) block sums in place
__global__ __launch_bounds__(64) void k_scan2(int* __restrict__ bsum, int nb){
    int t = threadIdx.x;
    int v = (t < nb) ? bsum[t] : 0;
    int s = v;
    #pragma unroll
    for (int off = 1; off < 64; off <<= 1){
        int u = __shfl_up(s, off);
        if (t >= off) s += u;
    }
    if (t < nb) bsum[t] = s - v;
}

// stage 3: add block base, emit offsets + cursor
__global__ __launch_bounds__(1024) void k_scan3(const int* __restrict__ loc,
        const int* __restrict__ bsum, int* __restrict__ offsets,
        int* __restrict__ cursor, int N){
    int i = blockIdx.x*1024 + threadIdx.x;
    if (i < N){
        int o = loc[i] + bsum[blockIdx.x];
        offsets[i] = o;
        cursor[i]  = o;
    }
}

// counting-sort edges by src, 2 edges/thread for MLP.
// record: {dst, ea0, ea1, ea2}, {ea3, ea4, e0, e1} with e_h = exp(lrelu(logit_h)).
__global__ __launch_bounds__(256) void k_scatter(const int* __restrict__ ei,
        const float* __restrict__ edge_attr, const float* __restrict__ consts,
        const float* __restrict__ a_i, const float* __restrict__ a_jn,
        int* __restrict__ cursor, float4* __restrict__ rec, int E){
    __shared__ float CK[12];
    if (threadIdx.x < 12) CK[threadIdx.x] = consts[threadIdx.x];
    __syncthreads();
    int eA = (blockIdx.x*256 + threadIdx.x)*2;
    int eB = eA + 1;
    bool vA = eA < E, vB = eB < E;
    int cA = vA ? eA : 0, cB = vB ? eB : 0;
    int sA = ei[cA], dA = ei[E + cA];
    int sB = ei[cB], dB = ei[E + cB];
    int posA = vA ? atomicAdd(cursor + sA, 1) : 0;
    int posB = vB ? atomicAdd(cursor + sB, 1) : 0;
    float eaA[NUM_BOND], eaB[NUM_BOND];
    #pragma unroll
    for (int b = 0; b < NUM_BOND; b++) eaA[b] = edge_attr[(size_t)cA*NUM_BOND + b];
    #pragma unroll
    for (int b = 0; b < NUM_BOND; b++) eaB[b] = edge_attr[(size_t)cB*NUM_BOND + b];
    float2 aiA = *(const float2*)(a_i + (size_t)sA*2);
    float2 aiB = *(const float2*)(a_i + (size_t)sB*2);
    float2 ajA = *(const float2*)(a_jn + (size_t)dA*2);
    float2 ajB = *(const float2*)(a_jn + (size_t)dB*2);
    float ajeA0 = CK[10], ajeA1 = CK[11], ajeB0 = CK[10], ajeB1 = CK[11];
    #pragma unroll
    for (int b = 0; b < NUM_BOND; b++){
        ajeA0 += eaA[b] * CK[2*b]; ajeA1 += eaA[b] * CK[2*b + 1];
        ajeB0 += eaB[b] * CK[2*b]; ajeB1 += eaB[b] * CK[2*b + 1];
    }
    float tA0 = aiA.x + ajA.x + ajeA0, tA1 = aiA.y + ajA.y + ajeA1;
    float tB0 = aiB.x + ajB.x + ajeB0, tB1 = aiB.y + ajB.y + ajeB1;
    float exA0 = __expf(fmaxf(tA0, NEG_SLOPE*tA0));
    float exA1 = __expf(fmaxf(tA1, NEG_SLOPE*tA1));
    float exB0 = __expf(fmaxf(tB0, NEG_SLOPE*tB0));
    float exB1 = __expf(fmaxf(tB1, NEG_SLOPE*tB1));
    if (vA){
        rec[(size_t)posA*2]     = make_float4(__int_as_float(dA), eaA[0], eaA[1], eaA[2]);
        rec[(size_t)posA*2 + 1] = make_float4(eaA[3], eaA[4], exA0, exA1);
    }
    if (vB){
        rec[(size_t)posB*2]     = make_float4(__int_as_float(dB), eaB[0], eaB[1], eaB[2]);
        rec[(size_t)posB*2 + 1] = make_float4(eaB[3], eaB[4], exB0, exB1);
    }
}

// one wave per node: chunk-4 software pipeline (rec 2 chunks ahead, hv 1 chunk ahead),
// pure-FMA inner loop (exp precomputed), ee factored into epilogue.
__global__ __launch_bounds__(256) void k_gat(const float4* __restrict__ rec,
        const int* __restrict__ offsets, const int* __restrict__ cnt,
        const unsigned* __restrict__ hb,
        const float* __restrict__ W_edge, const float* __restrict__ b_edge,
        const float* __restrict__ bias, float* __restrict__ out, int N){
    __shared__ float WE[NUM_BOND*128];
    __shared__ float BE[128];
    int t = threadIdx.x;
    for (int i = t; i < NUM_BOND*128; i += 256) WE[i] = W_edge[i];
    if (t < 128) BE[t] = b_edge[t];
    __syncthreads();
    int wid = t >> 6, lane = t & 63;
    int n = blockIdx.x*4 + wid;
    if (n >= N) return;

    int start = offsets[n], deg = cnt[n];

    float d0=0.f, d1=0.f, A0=0.f, A1=0.f;
    float eb00=0.f, eb01=0.f, eb02=0.f, eb03=0.f, eb04=0.f;
    float eb10=0.f, eb11=0.f, eb12=0.f, eb13=0.f, eb14=0.f;

    float4 ca[4], cb[4], na[4], nb[4];
    unsigned ch[4];

    // prologue: chunk 0 -> cur, chunk 1 -> nxt (masked slots zeroed: e=0 kills them)
    #pragma unroll
    for (int j = 0; j < 4; j++){
        if (j < deg){
            ca[j] = rec[(size_t)(start + j)*2];
            cb[j] = rec[(size_t)(start + j)*2 + 1];
        } else {
            ca[j] = make_float4(0,0,0,0); cb[j] = make_float4(0,0,0,0);
        }
        if (4 + j < deg){
            na[j] = rec[(size_t)(start + 4 + j)*2];
            nb[j] = rec[(size_t)(start + 4 + j)*2 + 1];
        } else {
            na[j] = make_float4(0,0,0,0); nb[j] = make_float4(0,0,0,0);
        }
    }
    #pragma unroll
    for (int j = 0; j < 4; j++)
        ch[j] = (j < deg) ? hb[(size_t)__float_as_uint(ca[j].x)*EMB + lane] : 0u;

    for (int c = 0; c < deg; c += 4){
        // issue hv for chunk c+4 (rec loaded one iteration ago)
        unsigned nh[4];
        #pragma unroll
        for (int j = 0; j < 4; j++)
            nh[j] = (c + 4 + j < deg) ? hb[(size_t)__float_as_uint(na[j].x)*EMB + lane] : 0u;
        // compute chunk c (hv issued one iteration ago)
        #pragma unroll
        for (int j = 0; j < 4; j++){
            float e0 = cb[j].z, e1 = cb[j].w;
            float hv0 = bf16lo(ch[j]), hv1 = bf16hi(ch[j]);
            d0 += e0; d1 += e1;
            A0 = fmaf(e0, hv0, A0); A1 = fmaf(e1, hv1, A1);
            eb00 = fmaf(e0, ca[j].y, eb00); eb01 = fmaf(e0, ca[j].z, eb01);
            eb02 = fmaf(e0, ca[j].w, eb02); eb03 = fmaf(e0, cb[j].x, eb03);
            eb04 = fmaf(e0, cb[j].y, eb04);
            eb10 = fmaf(e1, ca[j].y, eb10); eb11 = fmaf(e1, ca[j].z, eb11);
            eb12 = fmaf(e1, ca[j].w, eb12); eb13 = fmaf(e1, cb[j].x, eb13);
            eb14 = fmaf(e1, cb[j].y, eb14);
        }
        // rotate and load rec for chunk c+8
        #pragma unroll
        for (int j = 0; j < 4; j++){
            ca[j] = na[j]; cb[j] = nb[j]; ch[j] = nh[j];
            if (c + 8 + j < deg){
                na[j] = rec[(size_t)(start + c + 8 + j)*2];
                nb[j] = rec[(size_t)(start + c + 8 + j)*2 + 1];
            } else {
                na[j] = make_float4(0,0,0,0); nb[j] = make_float4(0,0,0,0);
            }
        }
    }
    float num0 = fmaf(d0, BE[lane],      A0);
    float num1 = fmaf(d1, BE[64 + lane], A1);
    num0 = fmaf(eb00, WE[lane],       num0);
    num0 = fmaf(eb01, WE[128 + lane], num0);
    num0 = fmaf(eb02, WE[256 + lane], num0);
    num0 = fmaf(eb03, WE[384 + lane], num0);
    num0 = fmaf(eb04, WE[512 + lane], num0);
    num1 = fmaf(eb10, WE[64 + lane],  num1);
    num1 = fmaf(eb11, WE[192 + lane], num1);
    num1 = fmaf(eb12, WE[320 + lane], num1);
    num1 = fmaf(eb13, WE[448 + lane], num1);
    num1 = fmaf(eb14, WE[576 + lane], num1);
    out[(size_t)n*EMB + lane] = 0.5f*(num0/(d0 + 1e-16f) + num1/(d1 + 1e-16f)) + bias[lane];
}

extern "C" void kernel_launch(void* const* d_in, const int* in_sizes, int n_in,
                              void* d_out, int out_size, void* d_ws, size_t ws_size,
                              hipStream_t stream){
    const float* x         = (const float*)d_in[0];
    const int*   ei        = (const int*)d_in[1];      // int32 [2][E]
    const float* edge_attr = (const float*)d_in[2];
    const float* W_lin     = (const float*)d_in[3];
    const float* b_lin     = (const float*)d_in[4];
    const float* W_edge    = (const float*)d_in[5];
    const float* b_edge    = (const float*)d_in[6];
    const float* att       = (const float*)d_in[7];
    const float* bias      = (const float*)d_in[8];
    int N = in_sizes[0] / EMB;
    int E = in_sizes[2] / NUM_BOND;
    int nb = (N + 1023) >> 10;

    float* ws     = (float*)d_ws;
    unsigned* hb  = (unsigned*)ws;                     // N*64 packed bf16x2
    float* a_i    = (float*)(hb + (size_t)N*EMB);      // N*2
    float* a_jn   = a_i + (size_t)N*2;                 // N*2
    float* consts = a_jn + (size_t)N*2;                // 16
    int*   cnt    = (int*)(consts + 16);               // N
    int*   loc    = cnt + N;                           // N
    int*   bsum   = loc + N;                           // 64
    int*   offsets= bsum + 64;                         // N
    int*   cursor = offsets + N;                       // N
    uintptr_t raddr = (uintptr_t)(cursor + N);
    raddr = (raddr + 15) & ~(uintptr_t)15;
    float4* rec   = (float4*)raddr;                    // E*2 float4 (32 B/edge)

    hipMemsetAsync(cnt, 0, (size_t)N*sizeof(int), stream);

    k_node   <<<2048, 256, 0, stream>>>(x, W_lin, b_lin, att, W_edge, b_edge,
                                        ei, E, hb, a_i, a_jn, consts, cnt, N);
    k_scan1  <<<nb, 1024, 0, stream>>>(cnt, loc, bsum, N);
    k_scan2  <<<1, 64, 0, stream>>>(bsum, nb);
    k_scan3  <<<nb, 1024, 0, stream>>>(loc, bsum, offsets, cursor, N);
    k_scatter<<<(E + 511)/512, 256, 0, stream>>>(ei, edge_attr, consts, a_i, a_jn,
                                                 cursor, rec, E);
    k_gat    <<<(N + 3)/4, 256, 0, stream>>>(rec, offsets, cnt, hb,
                                             W_edge, b_edge, bias, (float*)d_out, N);
}

// Round 9
// 258.423 us; speedup vs baseline: 1.2222x; 1.2222x over previous
//
#include <hip/hip_runtime.h>

#define EMB 64
#define HEADS 2
#define NUM_BOND 5
#define NEG_SLOPE 0.2f

__device__ __forceinline__ unsigned bf16rne(float f){
    unsigned u = __float_as_uint(f);
    return (u + 0x7FFFu + ((u >> 16) & 1u)) >> 16;
}
__device__ __forceinline__ float bf16lo(unsigned p){ return __uint_as_float(p << 16); }
__device__ __forceinline__ float bf16hi(unsigned p){ return __uint_as_float(p & 0xFFFF0000u); }

// fused: consts (block 0) + src histogram + node transform.
// hb = packed bf16 {head0|head1<<16}; a_i, a_jn stored RAW.
__global__ __launch_bounds__(256) void k_node(const float* __restrict__ x,
        const float* __restrict__ W_lin, const float* __restrict__ b_lin,
        const float* __restrict__ att,
        const float* __restrict__ W_edge, const float* __restrict__ b_edge,
        const int* __restrict__ ei, int E,
        unsigned* __restrict__ hb, float* __restrict__ a_i, float* __restrict__ a_jn,
        float* __restrict__ consts, int* __restrict__ cnt, int N){
    __shared__ float WL[EMB*HEADS*EMB];          // 32 KB
    int t = threadIdx.x;
    if (blockIdx.x == 0 && t < 12){              // consts[2b+h], consts[10+h]
        int h = t & 1;
        const float* aj = att + h*2*EMB + EMB;
        float s = 0.f;
        if (t < 10){
            int b = t >> 1;
            for (int c = 0; c < EMB; c++) s += W_edge[b*(HEADS*EMB) + h*EMB + c] * aj[c];
        } else {
            for (int c = 0; c < EMB; c++) s += b_edge[h*EMB + c] * aj[c];
        }
        consts[t] = s;
    }
    for (int e = blockIdx.x*256 + t; e < E; e += gridDim.x*256)
        atomicAdd(cnt + ei[e], 1);
    for (int i = t; i < EMB*HEADS*EMB; i += 256) WL[i] = W_lin[i];
    __syncthreads();
    int wid = t >> 6, lane = t & 63;
    for (int n = blockIdx.x*4 + wid; n < N; n += gridDim.x*4){
        float xv = x[(size_t)n*EMB + lane];
        float acc0 = b_lin[lane], acc1 = b_lin[64 + lane];
        #pragma unroll 8
        for (int k = 0; k < EMB; k++){
            float xk = __shfl(xv, k);
            acc0 += xk * WL[k*128 + lane];
            acc1 += xk * WL[k*128 + 64 + lane];
        }
        hb[(size_t)n*EMB + lane] = bf16rne(acc0) | (bf16rne(acc1) << 16);
        float p0 = acc0 * att[lane];
        float p1 = acc1 * att[128 + lane];
        float q0 = acc0 * att[64 + lane];
        float q1 = acc1 * att[192 + lane];
        for (int off = 32; off; off >>= 1){
            p0 += __shfl_xor(p0, off);
            p1 += __shfl_xor(p1, off);
            q0 += __shfl_xor(q0, off);
            q1 += __shfl_xor(q1, off);
        }
        if (lane == 0){
            a_i[n*2]  = p0; a_i[n*2+1]  = p1;
            a_jn[n*2] = q0; a_jn[n*2+1] = q1;
        }
    }
}

// hierarchical scan, stage 1: per-block (1024) exclusive scan + block sums
__global__ __launch_bounds__(1024) void k_scan1(const int* __restrict__ cnt,
        int* __restrict__ loc, int* __restrict__ bsum, int N){
    __shared__ int wsum[16];
    int t = threadIdx.x, lane = t & 63, wid = t >> 6;
    int i = blockIdx.x*1024 + t;
    int v = (i < N) ? cnt[i] : 0;
    int s = v;
    #pragma unroll
    for (int off = 1; off < 64; off <<= 1){
        int u = __shfl_up(s, off);
        if (lane >= off) s += u;
    }
    if (lane == 63) wsum[wid] = s;
    __syncthreads();
    if (t < 16){
        int w = wsum[t];
        #pragma unroll
        for (int off = 1; off < 16; off <<= 1){
            int u = __shfl_up(w, off);
            if (t >= off) w += u;
        }
        wsum[t] = w;
    }
    __syncthreads();
    int excl = (s - v) + (wid ? wsum[wid - 1] : 0);
    if (i < N) loc[i] = excl;
    if (t == 1023) bsum[blockIdx.x] = excl + v;
}

// stage 2: single wave exclusive-scans the (<=64) block sums in place
__global__ __launch_bounds__(64) void k_scan2(int* __restrict__ bsum, int nb){
    int t = threadIdx.x;
    int v = (t < nb) ? bsum[t] : 0;
    int s = v;
    #pragma unroll
    for (int off = 1; off < 64; off <<= 1){
        int u = __shfl_up(s, off);
        if (t >= off) s += u;
    }
    if (t < nb) bsum[t] = s - v;
}

// stage 3: add block base, emit offsets + cursor
__global__ __launch_bounds__(1024) void k_scan3(const int* __restrict__ loc,
        const int* __restrict__ bsum, int* __restrict__ offsets,
        int* __restrict__ cursor, int N){
    int i = blockIdx.x*1024 + threadIdx.x;
    if (i < N){
        int o = loc[i] + bsum[blockIdx.x];
        offsets[i] = o;
        cursor[i]  = o;
    }
}

// counting-sort edges by src, 2 edges/thread for MLP.
// record: {dst, ea0, ea1, ea2}, {ea3, ea4, e0, e1} with e_h = exp(lrelu(logit_h)).
__global__ __launch_bounds__(256) void k_scatter(const int* __restrict__ ei,
        const float* __restrict__ edge_attr, const float* __restrict__ consts,
        const float* __restrict__ a_i, const float* __restrict__ a_jn,
        int* __restrict__ cursor, float4* __restrict__ rec, int E){
    __shared__ float CK[12];
    if (threadIdx.x < 12) CK[threadIdx.x] = consts[threadIdx.x];
    __syncthreads();
    int eA = (blockIdx.x*256 + threadIdx.x)*2;
    int eB = eA + 1;
    bool vA = eA < E, vB = eB < E;
    int cA = vA ? eA : 0, cB = vB ? eB : 0;
    int sA = ei[cA], dA = ei[E + cA];
    int sB = ei[cB], dB = ei[E + cB];
    int posA = vA ? atomicAdd(cursor + sA, 1) : 0;
    int posB = vB ? atomicAdd(cursor + sB, 1) : 0;
    float eaA[NUM_BOND], eaB[NUM_BOND];
    #pragma unroll
    for (int b = 0; b < NUM_BOND; b++) eaA[b] = edge_attr[(size_t)cA*NUM_BOND + b];
    #pragma unroll
    for (int b = 0; b < NUM_BOND; b++) eaB[b] = edge_attr[(size_t)cB*NUM_BOND + b];
    float2 aiA = *(const float2*)(a_i + (size_t)sA*2);
    float2 aiB = *(const float2*)(a_i + (size_t)sB*2);
    float2 ajA = *(const float2*)(a_jn + (size_t)dA*2);
    float2 ajB = *(const float2*)(a_jn + (size_t)dB*2);
    float ajeA0 = CK[10], ajeA1 = CK[11], ajeB0 = CK[10], ajeB1 = CK[11];
    #pragma unroll
    for (int b = 0; b < NUM_BOND; b++){
        ajeA0 += eaA[b] * CK[2*b]; ajeA1 += eaA[b] * CK[2*b + 1];
        ajeB0 += eaB[b] * CK[2*b]; ajeB1 += eaB[b] * CK[2*b + 1];
    }
    float tA0 = aiA.x + ajA.x + ajeA0, tA1 = aiA.y + ajA.y + ajeA1;
    float tB0 = aiB.x + ajB.x + ajeB0, tB1 = aiB.y + ajB.y + ajeB1;
    float exA0 = __expf(fmaxf(tA0, NEG_SLOPE*tA0));
    float exA1 = __expf(fmaxf(tA1, NEG_SLOPE*tA1));
    float exB0 = __expf(fmaxf(tB0, NEG_SLOPE*tB0));
    float exB1 = __expf(fmaxf(tB1, NEG_SLOPE*tB1));
    if (vA){
        rec[(size_t)posA*2]     = make_float4(__int_as_float(dA), eaA[0], eaA[1], eaA[2]);
        rec[(size_t)posA*2 + 1] = make_float4(eaA[3], eaA[4], exA0, exA1);
    }
    if (vB){
        rec[(size_t)posB*2]     = make_float4(__int_as_float(dB), eaB[0], eaB[1], eaB[2]);
        rec[(size_t)posB*2 + 1] = make_float4(eaB[3], eaB[4], exB0, exB1);
    }
}

// one wave per node: sequential CSR walk, 1-ahead rolling prefetch (R7 form),
// pure-FMA inner loop (exp precomputed in record), ee factored into epilogue.
__global__ __launch_bounds__(256, 8) void k_gat(const float4* __restrict__ rec,
        const int* __restrict__ offsets, const int* __restrict__ cnt,
        const unsigned* __restrict__ hb,
        const float* __restrict__ W_edge, const float* __restrict__ b_edge,
        const float* __restrict__ bias, float* __restrict__ out, int N){
    __shared__ float WE[NUM_BOND*128];
    __shared__ float BE[128];
    int t = threadIdx.x;
    for (int i = t; i < NUM_BOND*128; i += 256) WE[i] = W_edge[i];
    if (t < 128) BE[t] = b_edge[t];
    __syncthreads();
    int wid = t >> 6, lane = t & 63;
    int n = blockIdx.x*4 + wid;
    if (n >= N) return;

    int start = offsets[n], deg = cnt[n];

    float d0=0.f, d1=0.f, A0=0.f, A1=0.f;
    float eb00=0.f, eb01=0.f, eb02=0.f, eb03=0.f, eb04=0.f;
    float eb10=0.f, eb11=0.f, eb12=0.f, eb13=0.f, eb14=0.f;

    float4 raN, rbN; unsigned hvN = 0;
    if (deg > 0){
        raN = rec[(size_t)start*2];
        rbN = rec[(size_t)start*2 + 1];
        hvN = hb[(size_t)__float_as_uint(raN.x)*EMB + lane];
    }
    for (int k = 0; k < deg; k++){
        float4 ra = raN, rb = rbN; unsigned hv = hvN;
        if (k + 1 < deg){
            raN = rec[(size_t)(start + k + 1)*2];
            rbN = rec[(size_t)(start + k + 1)*2 + 1];
            hvN = hb[(size_t)__float_as_uint(raN.x)*EMB + lane];
        }
        float e0 = rb.z, e1 = rb.w;
        float hv0 = bf16lo(hv), hv1 = bf16hi(hv);
        d0 += e0; d1 += e1;
        A0 = fmaf(e0, hv0, A0); A1 = fmaf(e1, hv1, A1);
        eb00 = fmaf(e0, ra.y, eb00); eb01 = fmaf(e0, ra.z, eb01);
        eb02 = fmaf(e0, ra.w, eb02); eb03 = fmaf(e0, rb.x, eb03);
        eb04 = fmaf(e0, rb.y, eb04);
        eb10 = fmaf(e1, ra.y, eb10); eb11 = fmaf(e1, ra.z, eb11);
        eb12 = fmaf(e1, ra.w, eb12); eb13 = fmaf(e1, rb.x, eb13);
        eb14 = fmaf(e1, rb.y, eb14);
    }
    float num0 = fmaf(d0, BE[lane],      A0);
    float num1 = fmaf(d1, BE[64 + lane], A1);
    num0 = fmaf(eb00, WE[lane],       num0);
    num0 = fmaf(eb01, WE[128 + lane], num0);
    num0 = fmaf(eb02, WE[256 + lane], num0);
    num0 = fmaf(eb03, WE[384 + lane], num0);
    num0 = fmaf(eb04, WE[512 + lane], num0);
    num1 = fmaf(eb10, WE[64 + lane],  num1);
    num1 = fmaf(eb11, WE[192 + lane], num1);
    num1 = fmaf(eb12, WE[320 + lane], num1);
    num1 = fmaf(eb13, WE[448 + lane], num1);
    num1 = fmaf(eb14, WE[576 + lane], num1);
    out[(size_t)n*EMB + lane] = 0.5f*(num0/(d0 + 1e-16f) + num1/(d1 + 1e-16f)) + bias[lane];
}

extern "C" void kernel_launch(void* const* d_in, const int* in_sizes, int n_in,
                              void* d_out, int out_size, void* d_ws, size_t ws_size,
                              hipStream_t stream){
    const float* x         = (const float*)d_in[0];
    const int*   ei        = (const int*)d_in[1];      // int32 [2][E]
    const float* edge_attr = (const float*)d_in[2];
    const float* W_lin     = (const float*)d_in[3];
    const float* b_lin     = (const float*)d_in[4];
    const float* W_edge    = (const float*)d_in[5];
    const float* b_edge    = (const float*)d_in[6];
    const float* att       = (const float*)d_in[7];
    const float* bias      = (const float*)d_in[8];
    int N = in_sizes[0] / EMB;
    int E = in_sizes[2] / NUM_BOND;
    int nb = (N + 1023) >> 10;

    float* ws     = (float*)d_ws;
    unsigned* hb  = (unsigned*)ws;                     // N*64 packed bf16x2
    float* a_i    = (float*)(hb + (size_t)N*EMB);      // N*2
    float* a_jn   = a_i + (size_t)N*2;                 // N*2
    float* consts = a_jn + (size_t)N*2;                // 16
    int*   cnt    = (int*)(consts + 16);               // N
    int*   loc    = cnt + N;                           // N
    int*   bsum   = loc + N;                           // 64
    int*   offsets= bsum + 64;                         // N
    int*   cursor = offsets + N;                       // N
    uintptr_t raddr = (uintptr_t)(cursor + N);
    raddr = (raddr + 15) & ~(uintptr_t)15;
    float4* rec   = (float4*)raddr;                    // E*2 float4 (32 B/edge)

    hipMemsetAsync(cnt, 0, (size_t)N*sizeof(int), stream);

    k_node   <<<2048, 256, 0, stream>>>(x, W_lin, b_lin, att, W_edge, b_edge,
                                        ei, E, hb, a_i, a_jn, consts, cnt, N);
    k_scan1  <<<nb, 1024, 0, stream>>>(cnt, loc, bsum, N);
    k_scan2  <<<1, 64, 0, stream>>>(bsum, nb);
    k_scan3  <<<nb, 1024, 0, stream>>>(loc, bsum, offsets, cursor, N);
    k_scatter<<<(E + 511)/512, 256, 0, stream>>>(ei, edge_attr, consts, a_i, a_jn,
                                                 cursor, rec, E);
    k_gat    <<<(N + 3)/4, 256, 0, stream>>>(rec, offsets, cnt, hb,
                                             W_edge, b_edge, bias, (float*)d_out, N);
}

// Round 10
// 219.627 us; speedup vs baseline: 1.4381x; 1.1766x over previous
//
#include <hip/hip_runtime.h>

#define EMB 64
#define HEADS 2
#define NUM_BOND 5
#define NEG_SLOPE 0.2f

__device__ __forceinline__ unsigned bf16rne(float f){
    unsigned u = __float_as_uint(f);
    return (u + 0x7FFFu + ((u >> 16) & 1u)) >> 16;
}
__device__ __forceinline__ float bf16lo(unsigned p){ return __uint_as_float(p << 16); }
__device__ __forceinline__ float bf16hi(unsigned p){ return __uint_as_float(p & 0xFFFF0000u); }

// one block, 256 threads: watt[k*4+w], bconst[4], consts[12]
// watt w: 0=i,h0  1=i,h1  2=j,h0  3=j,h1 ; att base (w&1)*128+(w>>1)*64 ; W col base (w&1)*64
__global__ void k_setup(const float* __restrict__ W_lin, const float* __restrict__ b_lin,
        const float* __restrict__ W_edge, const float* __restrict__ b_edge,
        const float* __restrict__ att,
        float* __restrict__ watt, float* __restrict__ bconst, float* __restrict__ consts){
    int t = threadIdx.x;
    int k = t >> 2, w = t & 3;
    const float* ab = att + (w & 1)*128 + (w >> 1)*64;
    float s = 0.f;
    for (int c = 0; c < EMB; c++) s += W_lin[k*128 + (w & 1)*64 + c] * ab[c];
    watt[t] = s;
    if (t < 4){
        const float* ab2 = att + (t & 1)*128 + (t >> 1)*64;
        float sb = 0.f;
        for (int c = 0; c < EMB; c++) sb += b_lin[(t & 1)*64 + c] * ab2[c];
        bconst[t] = sb;
    }
    if (t < 12){
        int h = t & 1;
        const float* aj = att + h*128 + 64;
        float sc = 0.f;
        if (t < 10){
            int b = t >> 1;
            for (int c = 0; c < EMB; c++) sc += W_edge[b*128 + h*64 + c] * aj[c];
        } else {
            for (int c = 0; c < EMB; c++) sc += b_edge[h*64 + c] * aj[c];
        }
        consts[t] = sc;
    }
}

// 8 nodes/wave: x transposed into LDS, per-k broadcast reads; att-dots folded into
// the k-loop via watt (a_i = x·(W@att_i) + b·att_i). Histogram fused.
__global__ __launch_bounds__(256) void k_node(const float* __restrict__ x,
        const float* __restrict__ W_lin, const float* __restrict__ b_lin,
        const float* __restrict__ watt, const float* __restrict__ bconst,
        const int* __restrict__ ei, int E,
        unsigned* __restrict__ hb, float* __restrict__ a_i, float* __restrict__ a_jn,
        int* __restrict__ cnt, int N){
    __shared__ float2 WL2[EMB*EMB];   // 32 KB: {W[k][c], W[k][64+c]}
    __shared__ float4 WATT[EMB];      // 1 KB
    __shared__ float  XT[4][EMB*10];  // 10.24 KB, stride-10 (bank-friendly, b64-aligned)
    int t = threadIdx.x;
    for (int e = blockIdx.x*256 + t; e < E; e += gridDim.x*256)
        atomicAdd(cnt + ei[e], 1);
    for (int i = t; i < EMB*EMB; i += 256){
        int k = i >> 6, c = i & 63;
        WL2[i] = make_float2(W_lin[k*128 + c], W_lin[k*128 + 64 + c]);
    }
    if (t < EMB) WATT[t] = ((const float4*)watt)[t];
    __syncthreads();

    int wid = t >> 6, lane = t & 63;
    float* xt = &XT[wid][0];
    float bl0 = b_lin[lane], bl1 = b_lin[64 + lane];
    float bc0 = bconst[0], bc1 = bconst[1], bc2 = bconst[2], bc3 = bconst[3];

    for (int base = (blockIdx.x*4 + wid)*8; base < N; base += gridDim.x*32){
        #pragma unroll
        for (int j = 0; j < 8; j++){
            int n = base + j; if (n >= N) n = N - 1;
            xt[lane*10 + j] = x[(size_t)n*EMB + lane];
        }
        float acc0[8], acc1[8], ai0[8], ai1[8], aj0[8], aj1[8];
        #pragma unroll
        for (int j = 0; j < 8; j++){
            acc0[j] = bl0; acc1[j] = bl1;
            ai0[j] = bc0; ai1[j] = bc1; aj0[j] = bc2; aj1[j] = bc3;
        }
        #pragma unroll 2
        for (int k = 0; k < EMB; k++){
            float2 w  = WL2[(k << 6) + lane];
            float4 wa = WATT[k];
            float2 x01 = *(const float2*)&xt[k*10];
            float2 x23 = *(const float2*)&xt[k*10 + 2];
            float2 x45 = *(const float2*)&xt[k*10 + 4];
            float2 x67 = *(const float2*)&xt[k*10 + 6];
            float xk[8] = {x01.x, x01.y, x23.x, x23.y, x45.x, x45.y, x67.x, x67.y};
            #pragma unroll
            for (int j = 0; j < 8; j++){
                acc0[j] = fmaf(xk[j], w.x,  acc0[j]);
                acc1[j] = fmaf(xk[j], w.y,  acc1[j]);
                ai0[j]  = fmaf(xk[j], wa.x, ai0[j]);
                ai1[j]  = fmaf(xk[j], wa.y, ai1[j]);
                aj0[j]  = fmaf(xk[j], wa.z, aj0[j]);
                aj1[j]  = fmaf(xk[j], wa.w, aj1[j]);
            }
        }
        #pragma unroll
        for (int j = 0; j < 8; j++){
            int n = base + j;
            if (n < N){
                hb[(size_t)n*EMB + lane] = bf16rne(acc0[j]) | (bf16rne(acc1[j]) << 16);
                if (lane == 0){
                    *(float2*)(a_i  + (size_t)n*2) = make_float2(ai0[j], ai1[j]);
                    *(float2*)(a_jn + (size_t)n*2) = make_float2(aj0[j], aj1[j]);
                }
            }
        }
    }
}

// hierarchical scan, stage 1: per-block (1024) exclusive scan + block sums
__global__ __launch_bounds__(1024) void k_scan1(const int* __restrict__ cnt,
        int* __restrict__ loc, int* __restrict__ bsum, int N){
    __shared__ int wsum[16];
    int t = threadIdx.x, lane = t & 63, wid = t >> 6;
    int i = blockIdx.x*1024 + t;
    int v = (i < N) ? cnt[i] : 0;
    int s = v;
    #pragma unroll
    for (int off = 1; off < 64; off <<= 1){
        int u = __shfl_up(s, off);
        if (lane >= off) s += u;
    }
    if (lane == 63) wsum[wid] = s;
    __syncthreads();
    if (t < 16){
        int w = wsum[t];
        #pragma unroll
        for (int off = 1; off < 16; off <<= 1){
            int u = __shfl_up(w, off);
            if (t >= off) w += u;
        }
        wsum[t] = w;
    }
    __syncthreads();
    int excl = (s - v) + (wid ? wsum[wid - 1] : 0);
    if (i < N) loc[i] = excl;
    if (t == 1023) bsum[blockIdx.x] = excl + v;
}

__global__ __launch_bounds__(64) void k_scan2(int* __restrict__ bsum, int nb){
    int t = threadIdx.x;
    int v = (t < nb) ? bsum[t] : 0;
    int s = v;
    #pragma unroll
    for (int off = 1; off < 64; off <<= 1){
        int u = __shfl_up(s, off);
        if (t >= off) s += u;
    }
    if (t < nb) bsum[t] = s - v;
}

__global__ __launch_bounds__(1024) void k_scan3(const int* __restrict__ loc,
        const int* __restrict__ bsum, int* __restrict__ offsets,
        int* __restrict__ cursor, int N){
    int i = blockIdx.x*1024 + threadIdx.x;
    if (i < N){
        int o = loc[i] + bsum[blockIdx.x];
        offsets[i] = o;
        cursor[i]  = o;
    }
}

// counting-sort, 2 edges/thread, 16-byte records:
// {dst|ea4<<16, e0|e1<<16, ea0|ea1<<16, ea2|ea3<<16}   (bf16 fields; dst<65536)
__global__ __launch_bounds__(256) void k_scatter(const int* __restrict__ ei,
        const float* __restrict__ edge_attr, const float* __restrict__ consts,
        const float* __restrict__ a_i, const float* __restrict__ a_jn,
        int* __restrict__ cursor, uint4* __restrict__ rec, int E){
    __shared__ float CK[12];
    if (threadIdx.x < 12) CK[threadIdx.x] = consts[threadIdx.x];
    __syncthreads();
    int eA = (blockIdx.x*256 + threadIdx.x)*2;
    int eB = eA + 1;
    bool vA = eA < E, vB = eB < E;
    int cA = vA ? eA : 0, cB = vB ? eB : 0;
    int sA = ei[cA], dA = ei[E + cA];
    int sB = ei[cB], dB = ei[E + cB];
    int posA = vA ? atomicAdd(cursor + sA, 1) : 0;
    int posB = vB ? atomicAdd(cursor + sB, 1) : 0;
    float eaA[NUM_BOND], eaB[NUM_BOND];
    #pragma unroll
    for (int b = 0; b < NUM_BOND; b++) eaA[b] = edge_attr[(size_t)cA*NUM_BOND + b];
    #pragma unroll
    for (int b = 0; b < NUM_BOND; b++) eaB[b] = edge_attr[(size_t)cB*NUM_BOND + b];
    float2 aiA = *(const float2*)(a_i + (size_t)sA*2);
    float2 aiB = *(const float2*)(a_i + (size_t)sB*2);
    float2 ajA = *(const float2*)(a_jn + (size_t)dA*2);
    float2 ajB = *(const float2*)(a_jn + (size_t)dB*2);
    float ajeA0 = CK[10], ajeA1 = CK[11], ajeB0 = CK[10], ajeB1 = CK[11];
    #pragma unroll
    for (int b = 0; b < NUM_BOND; b++){
        ajeA0 += eaA[b] * CK[2*b]; ajeA1 += eaA[b] * CK[2*b + 1];
        ajeB0 += eaB[b] * CK[2*b]; ajeB1 += eaB[b] * CK[2*b + 1];
    }
    float tA0 = aiA.x + ajA.x + ajeA0, tA1 = aiA.y + ajA.y + ajeA1;
    float tB0 = aiB.x + ajB.x + ajeB0, tB1 = aiB.y + ajB.y + ajeB1;
    float exA0 = __expf(fmaxf(tA0, NEG_SLOPE*tA0));
    float exA1 = __expf(fmaxf(tA1, NEG_SLOPE*tA1));
    float exB0 = __expf(fmaxf(tB0, NEG_SLOPE*tB0));
    float exB1 = __expf(fmaxf(tB1, NEG_SLOPE*tB1));
    if (vA){
        rec[posA] = make_uint4((unsigned)dA | (bf16rne(eaA[4]) << 16),
                               bf16rne(exA0) | (bf16rne(exA1) << 16),
                               bf16rne(eaA[0]) | (bf16rne(eaA[1]) << 16),
                               bf16rne(eaA[2]) | (bf16rne(eaA[3]) << 16));
    }
    if (vB){
        rec[posB] = make_uint4((unsigned)dB | (bf16rne(eaB[4]) << 16),
                               bf16rne(exB0) | (bf16rne(exB1) << 16),
                               bf16rne(eaB[0]) | (bf16rne(eaB[1]) << 16),
                               bf16rne(eaB[2]) | (bf16rne(eaB[3]) << 16));
    }
}

// one wave per node: sequential CSR walk over 16B records, 1-ahead prefetch,
// pure-FMA inner loop, ee factored into epilogue.
__global__ __launch_bounds__(256, 8) void k_gat(const uint4* __restrict__ rec,
        const int* __restrict__ offsets, const int* __restrict__ cnt,
        const unsigned* __restrict__ hb,
        const float* __restrict__ W_edge, const float* __restrict__ b_edge,
        const float* __restrict__ bias, float* __restrict__ out, int N){
    __shared__ float WE[NUM_BOND*128];
    __shared__ float BE[128];
    int t = threadIdx.x;
    for (int i = t; i < NUM_BOND*128; i += 256) WE[i] = W_edge[i];
    if (t < 128) BE[t] = b_edge[t];
    __syncthreads();
    int wid = t >> 6, lane = t & 63;
    int n = blockIdx.x*4 + wid;
    if (n >= N) return;

    int start = offsets[n], deg = cnt[n];

    float d0=0.f, d1=0.f, A0=0.f, A1=0.f;
    float eb00=0.f, eb01=0.f, eb02=0.f, eb03=0.f, eb04=0.f;
    float eb10=0.f, eb11=0.f, eb12=0.f, eb13=0.f, eb14=0.f;

    uint4 rN; unsigned hvN = 0;
    if (deg > 0){
        rN  = rec[start];
        hvN = hb[(size_t)(rN.x & 0xFFFFu)*EMB + lane];
    }
    for (int k = 0; k < deg; k++){
        uint4 r = rN; unsigned hv = hvN;
        if (k + 1 < deg){
            rN  = rec[start + k + 1];
            hvN = hb[(size_t)(rN.x & 0xFFFFu)*EMB + lane];
        }
        float e0 = bf16lo(r.y), e1 = bf16hi(r.y);
        float ea0 = bf16lo(r.z), ea1 = bf16hi(r.z);
        float ea2 = bf16lo(r.w), ea3 = bf16hi(r.w);
        float ea4 = bf16hi(r.x);
        float hv0 = bf16lo(hv), hv1 = bf16hi(hv);
        d0 += e0; d1 += e1;
        A0 = fmaf(e0, hv0, A0); A1 = fmaf(e1, hv1, A1);
        eb00 = fmaf(e0, ea0, eb00); eb01 = fmaf(e0, ea1, eb01);
        eb02 = fmaf(e0, ea2, eb02); eb03 = fmaf(e0, ea3, eb03);
        eb04 = fmaf(e0, ea4, eb04);
        eb10 = fmaf(e1, ea0, eb10); eb11 = fmaf(e1, ea1, eb11);
        eb12 = fmaf(e1, ea2, eb12); eb13 = fmaf(e1, ea3, eb13);
        eb14 = fmaf(e1, ea4, eb14);
    }
    float num0 = fmaf(d0, BE[lane],      A0);
    float num1 = fmaf(d1, BE[64 + lane], A1);
    num0 = fmaf(eb00, WE[lane],       num0);
    num0 = fmaf(eb01, WE[128 + lane], num0);
    num0 = fmaf(eb02, WE[256 + lane], num0);
    num0 = fmaf(eb03, WE[384 + lane], num0);
    num0 = fmaf(eb04, WE[512 + lane], num0);
    num1 = fmaf(eb10, WE[64 + lane],  num1);
    num1 = fmaf(eb11, WE[192 + lane], num1);
    num1 = fmaf(eb12, WE[320 + lane], num1);
    num1 = fmaf(eb13, WE[448 + lane], num1);
    num1 = fmaf(eb14, WE[576 + lane], num1);
    out[(size_t)n*EMB + lane] = 0.5f*(num0/(d0 + 1e-16f) + num1/(d1 + 1e-16f)) + bias[lane];
}

extern "C" void kernel_launch(void* const* d_in, const int* in_sizes, int n_in,
                              void* d_out, int out_size, void* d_ws, size_t ws_size,
                              hipStream_t stream){
    const float* x         = (const float*)d_in[0];
    const int*   ei        = (const int*)d_in[1];      // int32 [2][E]
    const float* edge_attr = (const float*)d_in[2];
    const float* W_lin     = (const float*)d_in[3];
    const float* b_lin     = (const float*)d_in[4];
    const float* W_edge    = (const float*)d_in[5];
    const float* b_edge    = (const float*)d_in[6];
    const float* att       = (const float*)d_in[7];
    const float* bias      = (const float*)d_in[8];
    int N = in_sizes[0] / EMB;          // 50000 (< 65536: dst packs into u16)
    int E = in_sizes[2] / NUM_BOND;
    int nb = (N + 1023) >> 10;

    float* ws     = (float*)d_ws;
    unsigned* hb  = (unsigned*)ws;                     // N*64 packed bf16x2
    float* a_i    = (float*)(hb + (size_t)N*EMB);      // N*2
    float* a_jn   = a_i + (size_t)N*2;                 // N*2
    float* watt   = a_jn + (size_t)N*2;                // 256
    float* bconst = watt + 256;                        // 4
    float* consts = bconst + 4;                        // 12
    int*   cnt    = (int*)(consts + 12);               // N
    int*   loc    = cnt + N;                           // N
    int*   bsum   = loc + N;                           // 64
    int*   offsets= bsum + 64;                         // N
    int*   cursor = offsets + N;                       // N
    uintptr_t raddr = (uintptr_t)(cursor + N);
    raddr = (raddr + 15) & ~(uintptr_t)15;
    uint4* rec    = (uint4*)raddr;                     // E * 16 B

    hipMemsetAsync(cnt, 0, (size_t)N*sizeof(int), stream);

    k_setup  <<<1, 256, 0, stream>>>(W_lin, b_lin, W_edge, b_edge, att,
                                     watt, bconst, consts);
    k_node   <<<(N + 31)/32, 256, 0, stream>>>(x, W_lin, b_lin, watt, bconst,
                                               ei, E, hb, a_i, a_jn, cnt, N);
    k_scan1  <<<nb, 1024, 0, stream>>>(cnt, loc, bsum, N);
    k_scan2  <<<1, 64, 0, stream>>>(bsum, nb);
    k_scan3  <<<nb, 1024, 0, stream>>>(loc, bsum, offsets, cursor, N);
    k_scatter<<<(E + 511)/512, 256, 0, stream>>>(ei, edge_attr, consts, a_i, a_jn,
                                                 cursor, rec, E);
    k_gat    <<<(N + 3)/4, 256, 0, stream>>>(rec, offsets, cnt, hb,
                                             W_edge, b_edge, bias, (float*)d_out, N);
}

// Round 11
// 188.882 us; speedup vs baseline: 1.6722x; 1.1628x over previous
//
#include <hip/hip_runtime.h>

#define EMB 64
#define HEADS 2
#define NUM_BOND 5
#define NEG_SLOPE 0.2f

__device__ __forceinline__ unsigned bf16rne(float f){
    unsigned u = __float_as_uint(f);
    return (u + 0x7FFFu + ((u >> 16) & 1u)) >> 16;
}
__device__ __forceinline__ float bf16lo(unsigned p){ return __uint_as_float(p << 16); }
__device__ __forceinline__ float bf16hi(unsigned p){ return __uint_as_float(p & 0xFFFF0000u); }

// one block, 256 threads: watt[k*4+w], bconst[4], consts[12]
__global__ void k_setup(const float* __restrict__ W_lin, const float* __restrict__ b_lin,
        const float* __restrict__ W_edge, const float* __restrict__ b_edge,
        const float* __restrict__ att,
        float* __restrict__ watt, float* __restrict__ bconst, float* __restrict__ consts){
    int t = threadIdx.x;
    int k = t >> 2, w = t & 3;
    const float* ab = att + (w & 1)*128 + (w >> 1)*64;
    float s = 0.f;
    for (int c = 0; c < EMB; c++) s += W_lin[k*128 + (w & 1)*64 + c] * ab[c];
    watt[t] = s;
    if (t < 4){
        const float* ab2 = att + (t & 1)*128 + (t >> 1)*64;
        float sb = 0.f;
        for (int c = 0; c < EMB; c++) sb += b_lin[(t & 1)*64 + c] * ab2[c];
        bconst[t] = sb;
    }
    if (t < 12){
        int h = t & 1;
        const float* aj = att + h*128 + 64;
        float sc = 0.f;
        if (t < 10){
            int b = t >> 1;
            for (int c = 0; c < EMB; c++) sc += W_edge[b*128 + h*64 + c] * aj[c];
        } else {
            for (int c = 0; c < EMB; c++) sc += b_edge[h*64 + c] * aj[c];
        }
        consts[t] = sc;
    }
}

// 8 nodes/wave: x transposed into LDS, per-k broadcast reads; att-dots folded into
// the k-loop via watt (a_i = x·(W@att_i) + b·att_i). Histogram fused.
__global__ __launch_bounds__(256) void k_node(const float* __restrict__ x,
        const float* __restrict__ W_lin, const float* __restrict__ b_lin,
        const float* __restrict__ watt, const float* __restrict__ bconst,
        const int* __restrict__ ei, int E,
        unsigned* __restrict__ hb, float* __restrict__ a_i, float* __restrict__ a_jn,
        int* __restrict__ cnt, int N){
    __shared__ float2 WL2[EMB*EMB];   // 32 KB: {W[k][c], W[k][64+c]}
    __shared__ float4 WATT[EMB];      // 1 KB
    __shared__ float  XT[4][EMB*10];  // 10.24 KB, stride-10
    int t = threadIdx.x;
    for (int e = blockIdx.x*256 + t; e < E; e += gridDim.x*256)
        atomicAdd(cnt + ei[e], 1);
    for (int i = t; i < EMB*EMB; i += 256){
        int k = i >> 6, c = i & 63;
        WL2[i] = make_float2(W_lin[k*128 + c], W_lin[k*128 + 64 + c]);
    }
    if (t < EMB) WATT[t] = ((const float4*)watt)[t];
    __syncthreads();

    int wid = t >> 6, lane = t & 63;
    float* xt = &XT[wid][0];
    float bl0 = b_lin[lane], bl1 = b_lin[64 + lane];
    float bc0 = bconst[0], bc1 = bconst[1], bc2 = bconst[2], bc3 = bconst[3];

    for (int base = (blockIdx.x*4 + wid)*8; base < N; base += gridDim.x*32){
        #pragma unroll
        for (int j = 0; j < 8; j++){
            int n = base + j; if (n >= N) n = N - 1;
            xt[lane*10 + j] = x[(size_t)n*EMB + lane];
        }
        float acc0[8], acc1[8], ai0[8], ai1[8], aj0[8], aj1[8];
        #pragma unroll
        for (int j = 0; j < 8; j++){
            acc0[j] = bl0; acc1[j] = bl1;
            ai0[j] = bc0; ai1[j] = bc1; aj0[j] = bc2; aj1[j] = bc3;
        }
        #pragma unroll 2
        for (int k = 0; k < EMB; k++){
            float2 w  = WL2[(k << 6) + lane];
            float4 wa = WATT[k];
            float2 x01 = *(const float2*)&xt[k*10];
            float2 x23 = *(const float2*)&xt[k*10 + 2];
            float2 x45 = *(const float2*)&xt[k*10 + 4];
            float2 x67 = *(const float2*)&xt[k*10 + 6];
            float xk[8] = {x01.x, x01.y, x23.x, x23.y, x45.x, x45.y, x67.x, x67.y};
            #pragma unroll
            for (int j = 0; j < 8; j++){
                acc0[j] = fmaf(xk[j], w.x,  acc0[j]);
                acc1[j] = fmaf(xk[j], w.y,  acc1[j]);
                ai0[j]  = fmaf(xk[j], wa.x, ai0[j]);
                ai1[j]  = fmaf(xk[j], wa.y, ai1[j]);
                aj0[j]  = fmaf(xk[j], wa.z, aj0[j]);
                aj1[j]  = fmaf(xk[j], wa.w, aj1[j]);
            }
        }
        #pragma unroll
        for (int j = 0; j < 8; j++){
            int n = base + j;
            if (n < N){
                hb[(size_t)n*EMB + lane] = bf16rne(acc0[j]) | (bf16rne(acc1[j]) << 16);
                if (lane == 0){
                    *(float2*)(a_i  + (size_t)n*2) = make_float2(ai0[j], ai1[j]);
                    *(float2*)(a_jn + (size_t)n*2) = make_float2(aj0[j], aj1[j]);
                }
            }
        }
    }
}

// hierarchical scan
__global__ __launch_bounds__(1024) void k_scan1(const int* __restrict__ cnt,
        int* __restrict__ loc, int* __restrict__ bsum, int N){
    __shared__ int wsum[16];
    int t = threadIdx.x, lane = t & 63, wid = t >> 6;
    int i = blockIdx.x*1024 + t;
    int v = (i < N) ? cnt[i] : 0;
    int s = v;
    #pragma unroll
    for (int off = 1; off < 64; off <<= 1){
        int u = __shfl_up(s, off);
        if (lane >= off) s += u;
    }
    if (lane == 63) wsum[wid] = s;
    __syncthreads();
    if (t < 16){
        int w = wsum[t];
        #pragma unroll
        for (int off = 1; off < 16; off <<= 1){
            int u = __shfl_up(w, off);
            if (t >= off) w += u;
        }
        wsum[t] = w;
    }
    __syncthreads();
    int excl = (s - v) + (wid ? wsum[wid - 1] : 0);
    if (i < N) loc[i] = excl;
    if (t == 1023) bsum[blockIdx.x] = excl + v;
}

__global__ __launch_bounds__(64) void k_scan2(int* __restrict__ bsum, int nb){
    int t = threadIdx.x;
    int v = (t < nb) ? bsum[t] : 0;
    int s = v;
    #pragma unroll
    for (int off = 1; off < 64; off <<= 1){
        int u = __shfl_up(s, off);
        if (t >= off) s += u;
    }
    if (t < nb) bsum[t] = s - v;
}

__global__ __launch_bounds__(1024) void k_scan3(const int* __restrict__ loc,
        const int* __restrict__ bsum, int* __restrict__ offsets,
        int* __restrict__ cursor, int N){
    int i = blockIdx.x*1024 + threadIdx.x;
    if (i < N){
        int o = loc[i] + bsum[blockIdx.x];
        offsets[i] = o;
        cursor[i]  = o;
    }
}

// counting-sort, 2 edges/thread, 16-byte records:
// {dst|ea4<<16, e0|e1<<16, ea0|ea1<<16, ea2|ea3<<16}
__global__ __launch_bounds__(256) void k_scatter(const int* __restrict__ ei,
        const float* __restrict__ edge_attr, const float* __restrict__ consts,
        const float* __restrict__ a_i, const float* __restrict__ a_jn,
        int* __restrict__ cursor, uint4* __restrict__ rec, int E){
    __shared__ float CK[12];
    if (threadIdx.x < 12) CK[threadIdx.x] = consts[threadIdx.x];
    __syncthreads();
    int eA = (blockIdx.x*256 + threadIdx.x)*2;
    int eB = eA + 1;
    bool vA = eA < E, vB = eB < E;
    int cA = vA ? eA : 0, cB = vB ? eB : 0;
    int sA = ei[cA], dA = ei[E + cA];
    int sB = ei[cB], dB = ei[E + cB];
    int posA = vA ? atomicAdd(cursor + sA, 1) : 0;
    int posB = vB ? atomicAdd(cursor + sB, 1) : 0;
    float eaA[NUM_BOND], eaB[NUM_BOND];
    #pragma unroll
    for (int b = 0; b < NUM_BOND; b++) eaA[b] = edge_attr[(size_t)cA*NUM_BOND + b];
    #pragma unroll
    for (int b = 0; b < NUM_BOND; b++) eaB[b] = edge_attr[(size_t)cB*NUM_BOND + b];
    float2 aiA = *(const float2*)(a_i + (size_t)sA*2);
    float2 aiB = *(const float2*)(a_i + (size_t)sB*2);
    float2 ajA = *(const float2*)(a_jn + (size_t)dA*2);
    float2 ajB = *(const float2*)(a_jn + (size_t)dB*2);
    float ajeA0 = CK[10], ajeA1 = CK[11], ajeB0 = CK[10], ajeB1 = CK[11];
    #pragma unroll
    for (int b = 0; b < NUM_BOND; b++){
        ajeA0 += eaA[b] * CK[2*b]; ajeA1 += eaA[b] * CK[2*b + 1];
        ajeB0 += eaB[b] * CK[2*b]; ajeB1 += eaB[b] * CK[2*b + 1];
    }
    float tA0 = aiA.x + ajA.x + ajeA0, tA1 = aiA.y + ajA.y + ajeA1;
    float tB0 = aiB.x + ajB.x + ajeB0, tB1 = aiB.y + ajB.y + ajeB1;
    float exA0 = __expf(fmaxf(tA0, NEG_SLOPE*tA0));
    float exA1 = __expf(fmaxf(tA1, NEG_SLOPE*tA1));
    float exB0 = __expf(fmaxf(tB0, NEG_SLOPE*tB0));
    float exB1 = __expf(fmaxf(tB1, NEG_SLOPE*tB1));
    if (vA){
        rec[posA] = make_uint4((unsigned)dA | (bf16rne(eaA[4]) << 16),
                               bf16rne(exA0) | (bf16rne(exA1) << 16),
                               bf16rne(eaA[0]) | (bf16rne(eaA[1]) << 16),
                               bf16rne(eaA[2]) | (bf16rne(eaA[3]) << 16));
    }
    if (vB){
        rec[posB] = make_uint4((unsigned)dB | (bf16rne(eaB[4]) << 16),
                               bf16rne(exB0) | (bf16rne(exB1) << 16),
                               bf16rne(eaB[0]) | (bf16rne(eaB[1]) << 16),
                               bf16rne(eaB[2]) | (bf16rne(eaB[3]) << 16));
    }
}

// TWO nodes per wave: each half-wave (32 lanes) walks one node's CSR list.
// Lane l covers channels 2l, 2l+1 via one b64 hb load. Branch-free clamped
// 1-ahead prefetch. Pure-FMA inner loop; ee factored into epilogue.
__global__ __launch_bounds__(256, 8) void k_gat(const uint4* __restrict__ rec,
        const int* __restrict__ offsets, const int* __restrict__ cnt,
        const unsigned* __restrict__ hb,
        const float* __restrict__ W_edge, const float* __restrict__ b_edge,
        const float* __restrict__ bias, float* __restrict__ out, int N){
    __shared__ float WE[NUM_BOND*128];
    __shared__ float BE[128];
    int t = threadIdx.x;
    for (int i = t; i < NUM_BOND*128; i += 256) WE[i] = W_edge[i];
    if (t < 128) BE[t] = b_edge[t];
    __syncthreads();
    int n = blockIdx.x*8 + (t >> 5);     // 8 half-waves per block
    int l = t & 31;                      // channels c0=2l, c1=2l+1
    if (n >= N) return;

    int start = offsets[n], deg = cnt[n];

    float d0=0.f, d1=0.f;
    float A00=0.f, A01=0.f, A10=0.f, A11=0.f;   // A[head][chan]
    float eb00=0.f, eb01=0.f, eb02=0.f, eb03=0.f, eb04=0.f;
    float eb10=0.f, eb11=0.f, eb12=0.f, eb13=0.f, eb14=0.f;

    uint4 rN; uint2 hvN = make_uint2(0u, 0u);
    if (deg > 0){
        rN  = rec[start];
        hvN = *(const uint2*)(hb + (size_t)(rN.x & 0xFFFFu)*EMB + 2*l);
    }
    for (int k = 0; k < deg; k++){
        uint4 r = rN; uint2 hv = hvN;
        int kn = (k + 1 < deg) ? (k + 1) : k;      // clamped, branch-free
        rN  = rec[start + kn];
        hvN = *(const uint2*)(hb + (size_t)(rN.x & 0xFFFFu)*EMB + 2*l);
        float e0 = bf16lo(r.y), e1 = bf16hi(r.y);
        float ea0 = bf16lo(r.z), ea1 = bf16hi(r.z);
        float ea2 = bf16lo(r.w), ea3 = bf16hi(r.w);
        float ea4 = bf16hi(r.x);
        float h00 = bf16lo(hv.x), h10 = bf16hi(hv.x);   // chan c0: head0, head1
        float h01 = bf16lo(hv.y), h11 = bf16hi(hv.y);   // chan c1
        d0 += e0; d1 += e1;
        A00 = fmaf(e0, h00, A00); A01 = fmaf(e0, h01, A01);
        A10 = fmaf(e1, h10, A10); A11 = fmaf(e1, h11, A11);
        eb00 = fmaf(e0, ea0, eb00); eb01 = fmaf(e0, ea1, eb01);
        eb02 = fmaf(e0, ea2, eb02); eb03 = fmaf(e0, ea3, eb03);
        eb04 = fmaf(e0, ea4, eb04);
        eb10 = fmaf(e1, ea0, eb10); eb11 = fmaf(e1, ea1, eb11);
        eb12 = fmaf(e1, ea2, eb12); eb13 = fmaf(e1, ea3, eb13);
        eb14 = fmaf(e1, ea4, eb14);
    }
    int c0 = 2*l, c1 = 2*l + 1;
    float num00 = fmaf(d0, BE[c0], A00);
    float num01 = fmaf(d0, BE[c1], A01);
    float num10 = fmaf(d1, BE[64 + c0], A10);
    float num11 = fmaf(d1, BE[64 + c1], A11);
    num00 = fmaf(eb00, WE[c0],       num00); num01 = fmaf(eb00, WE[c1],       num01);
    num00 = fmaf(eb01, WE[128 + c0], num00); num01 = fmaf(eb01, WE[128 + c1], num01);
    num00 = fmaf(eb02, WE[256 + c0], num00); num01 = fmaf(eb02, WE[256 + c1], num01);
    num00 = fmaf(eb03, WE[384 + c0], num00); num01 = fmaf(eb03, WE[384 + c1], num01);
    num00 = fmaf(eb04, WE[512 + c0], num00); num01 = fmaf(eb04, WE[512 + c1], num01);
    num10 = fmaf(eb10, WE[64 + c0],  num10); num11 = fmaf(eb10, WE[64 + c1],  num11);
    num10 = fmaf(eb11, WE[192 + c0], num10); num11 = fmaf(eb11, WE[192 + c1], num11);
    num10 = fmaf(eb12, WE[320 + c0], num10); num11 = fmaf(eb12, WE[320 + c1], num11);
    num10 = fmaf(eb13, WE[448 + c0], num10); num11 = fmaf(eb13, WE[448 + c1], num11);
    num10 = fmaf(eb14, WE[576 + c0], num10); num11 = fmaf(eb14, WE[576 + c1], num11);
    float id0 = 1.f/(d0 + 1e-16f), id1 = 1.f/(d1 + 1e-16f);
    float r0 = 0.5f*(num00*id0 + num10*id1) + bias[c0];
    float r1 = 0.5f*(num01*id0 + num11*id1) + bias[c1];
    *(float2*)(out + (size_t)n*EMB + c0) = make_float2(r0, r1);
}

extern "C" void kernel_launch(void* const* d_in, const int* in_sizes, int n_in,
                              void* d_out, int out_size, void* d_ws, size_t ws_size,
                              hipStream_t stream){
    const float* x         = (const float*)d_in[0];
    const int*   ei        = (const int*)d_in[1];      // int32 [2][E]
    const float* edge_attr = (const float*)d_in[2];
    const float* W_lin     = (const float*)d_in[3];
    const float* b_lin     = (const float*)d_in[4];
    const float* W_edge    = (const float*)d_in[5];
    const float* b_edge    = (const float*)d_in[6];
    const float* att       = (const float*)d_in[7];
    const float* bias      = (const float*)d_in[8];
    int N = in_sizes[0] / EMB;          // 50000 (< 65536: dst packs into u16)
    int E = in_sizes[2] / NUM_BOND;
    int nb = (N + 1023) >> 10;

    float* ws     = (float*)d_ws;
    unsigned* hb  = (unsigned*)ws;                     // N*64 packed bf16x2
    float* a_i    = (float*)(hb + (size_t)N*EMB);      // N*2
    float* a_jn   = a_i + (size_t)N*2;                 // N*2
    float* watt   = a_jn + (size_t)N*2;                // 256
    float* bconst = watt + 256;                        // 4
    float* consts = bconst + 4;                        // 12
    int*   cnt    = (int*)(consts + 12);               // N
    int*   loc    = cnt + N;                           // N
    int*   bsum   = loc + N;                           // 64
    int*   offsets= bsum + 64;                         // N
    int*   cursor = offsets + N;                       // N
    uintptr_t raddr = (uintptr_t)(cursor + N);
    raddr = (raddr + 15) & ~(uintptr_t)15;
    uint4* rec    = (uint4*)raddr;                     // E * 16 B

    hipMemsetAsync(cnt, 0, (size_t)N*sizeof(int), stream);

    k_setup  <<<1, 256, 0, stream>>>(W_lin, b_lin, W_edge, b_edge, att,
                                     watt, bconst, consts);
    k_node   <<<(N + 31)/32, 256, 0, stream>>>(x, W_lin, b_lin, watt, bconst,
                                               ei, E, hb, a_i, a_jn, cnt, N);
    k_scan1  <<<nb, 1024, 0, stream>>>(cnt, loc, bsum, N);
    k_scan2  <<<1, 64, 0, stream>>>(bsum, nb);
    k_scan3  <<<nb, 1024, 0, stream>>>(loc, bsum, offsets, cursor, N);
    k_scatter<<<(E + 511)/512, 256, 0, stream>>>(ei, edge_attr, consts, a_i, a_jn,
                                                 cursor, rec, E);
    k_gat    <<<(N + 7)/8, 256, 0, stream>>>(rec, offsets, cnt, hb,
                                             W_edge, b_edge, bias, (float*)d_out, N);
}

// Round 12
// 167.239 us; speedup vs baseline: 1.8886x; 1.1294x over previous
//
#include <hip/hip_runtime.h>

#define EMB 64
#define HEADS 2
#define NUM_BOND 5
#define NEG_SLOPE 0.2f

__device__ __forceinline__ unsigned bf16rne(float f){
    unsigned u = __float_as_uint(f);
    return (u + 0x7FFFu + ((u >> 16) & 1u)) >> 16;
}
__device__ __forceinline__ float bf16lo(unsigned p){ return __uint_as_float(p << 16); }
__device__ __forceinline__ float bf16hi(unsigned p){ return __uint_as_float(p & 0xFFFF0000u); }

// one block, 256 threads: watt[k*4+w], bconst[4], consts[12]
__global__ void k_setup(const float* __restrict__ W_lin, const float* __restrict__ b_lin,
        const float* __restrict__ W_edge, const float* __restrict__ b_edge,
        const float* __restrict__ att,
        float* __restrict__ watt, float* __restrict__ bconst, float* __restrict__ consts){
    int t = threadIdx.x;
    int k = t >> 2, w = t & 3;
    const float* ab = att + (w & 1)*128 + (w >> 1)*64;
    float s = 0.f;
    for (int c = 0; c < EMB; c++) s += W_lin[k*128 + (w & 1)*64 + c] * ab[c];
    watt[t] = s;
    if (t < 4){
        const float* ab2 = att + (t & 1)*128 + (t >> 1)*64;
        float sb = 0.f;
        for (int c = 0; c < EMB; c++) sb += b_lin[(t & 1)*64 + c] * ab2[c];
        bconst[t] = sb;
    }
    if (t < 12){
        int h = t & 1;
        const float* aj = att + h*128 + 64;
        float sc = 0.f;
        if (t < 10){
            int b = t >> 1;
            for (int c = 0; c < EMB; c++) sc += W_edge[b*128 + h*64 + c] * aj[c];
        } else {
            for (int c = 0; c < EMB; c++) sc += b_edge[h*64 + c] * aj[c];
        }
        consts[t] = sc;
    }
}

// 8 nodes/wave. W_lin/watt streamed from global (L1-resident, 32KB+1KB);
// only the per-wave x-transpose lives in LDS (10.25 KB) -> high occupancy.
// att-dots folded into the k-loop via watt. Histogram fused.
__global__ __launch_bounds__(256) void k_node(const float* __restrict__ x,
        const float* __restrict__ W_lin, const float* __restrict__ b_lin,
        const float* __restrict__ watt, const float* __restrict__ bconst,
        const int* __restrict__ ei, int E,
        unsigned* __restrict__ hb, float* __restrict__ a_i, float* __restrict__ a_jn,
        int* __restrict__ cnt, int N){
    __shared__ float XT[4][EMB*10];   // 10.24 KB, stride-10 (2-way bank alias = free)
    int t = threadIdx.x;
    for (int e = blockIdx.x*256 + t; e < E; e += gridDim.x*256)
        atomicAdd(cnt + ei[e], 1);

    int wid = t >> 6, lane = t & 63;
    float* xt = &XT[wid][0];
    float bl0 = b_lin[lane], bl1 = b_lin[64 + lane];
    float bc0 = bconst[0], bc1 = bconst[1], bc2 = bconst[2], bc3 = bconst[3];

    for (int base = (blockIdx.x*4 + wid)*8; base < N; base += gridDim.x*32){
        #pragma unroll
        for (int j = 0; j < 8; j++){
            int n = base + j; if (n >= N) n = N - 1;
            xt[lane*10 + j] = x[(size_t)n*EMB + lane];   // wave-private LDS, no barrier
        }
        float acc0[8], acc1[8], ai0[8], ai1[8], aj0[8], aj1[8];
        #pragma unroll
        for (int j = 0; j < 8; j++){
            acc0[j] = bl0; acc1[j] = bl1;
            ai0[j] = bc0; ai1[j] = bc1; aj0[j] = bc2; aj1[j] = bc3;
        }
        #pragma unroll 4
        for (int k = 0; k < EMB; k++){
            float w0 = W_lin[k*128 + lane];          // L1-hit stream
            float w1 = W_lin[k*128 + 64 + lane];
            float4 wa = *(const float4*)(watt + k*4); // uniform -> scalar load
            float2 x01 = *(const float2*)&xt[k*10];
            float2 x23 = *(const float2*)&xt[k*10 + 2];
            float2 x45 = *(const float2*)&xt[k*10 + 4];
            float2 x67 = *(const float2*)&xt[k*10 + 6];
            float xk[8] = {x01.x, x01.y, x23.x, x23.y, x45.x, x45.y, x67.x, x67.y};
            #pragma unroll
            for (int j = 0; j < 8; j++){
                acc0[j] = fmaf(xk[j], w0, acc0[j]);
                acc1[j] = fmaf(xk[j], w1, acc1[j]);
                ai0[j]  = fmaf(xk[j], wa.x, ai0[j]);
                ai1[j]  = fmaf(xk[j], wa.y, ai1[j]);
                aj0[j]  = fmaf(xk[j], wa.z, aj0[j]);
                aj1[j]  = fmaf(xk[j], wa.w, aj1[j]);
            }
        }
        #pragma unroll
        for (int j = 0; j < 8; j++){
            int n = base + j;
            if (n < N){
                hb[(size_t)n*EMB + lane] = bf16rne(acc0[j]) | (bf16rne(acc1[j]) << 16);
                if (lane == 0){
                    *(float2*)(a_i  + (size_t)n*2) = make_float2(ai0[j], ai1[j]);
                    *(float2*)(a_jn + (size_t)n*2) = make_float2(aj0[j], aj1[j]);
                }
            }
        }
    }
}

// hierarchical scan
__global__ __launch_bounds__(1024) void k_scan1(const int* __restrict__ cnt,
        int* __restrict__ loc, int* __restrict__ bsum, int N){
    __shared__ int wsum[16];
    int t = threadIdx.x, lane = t & 63, wid = t >> 6;
    int i = blockIdx.x*1024 + t;
    int v = (i < N) ? cnt[i] : 0;
    int s = v;
    #pragma unroll
    for (int off = 1; off < 64; off <<= 1){
        int u = __shfl_up(s, off);
        if (lane >= off) s += u;
    }
    if (lane == 63) wsum[wid] = s;
    __syncthreads();
    if (t < 16){
        int w = wsum[t];
        #pragma unroll
        for (int off = 1; off < 16; off <<= 1){
            int u = __shfl_up(w, off);
            if (t >= off) w += u;
        }
        wsum[t] = w;
    }
    __syncthreads();
    int excl = (s - v) + (wid ? wsum[wid - 1] : 0);
    if (i < N) loc[i] = excl;
    if (t == 1023) bsum[blockIdx.x] = excl + v;
}

__global__ __launch_bounds__(64) void k_scan2(int* __restrict__ bsum, int nb){
    int t = threadIdx.x;
    int v = (t < nb) ? bsum[t] : 0;
    int s = v;
    #pragma unroll
    for (int off = 1; off < 64; off <<= 1){
        int u = __shfl_up(s, off);
        if (t >= off) s += u;
    }
    if (t < nb) bsum[t] = s - v;
}

__global__ __launch_bounds__(1024) void k_scan3(const int* __restrict__ loc,
        const int* __restrict__ bsum, int* __restrict__ offsets,
        int* __restrict__ cursor, int N){
    int i = blockIdx.x*1024 + threadIdx.x;
    if (i < N){
        int o = loc[i] + bsum[blockIdx.x];
        offsets[i] = o;
        cursor[i]  = o;
    }
}

// counting-sort, 2 edges/thread, 16-byte records:
// {dst|ea4<<16, e0|e1<<16, ea0|ea1<<16, ea2|ea3<<16}
__global__ __launch_bounds__(256) void k_scatter(const int* __restrict__ ei,
        const float* __restrict__ edge_attr, const float* __restrict__ consts,
        const float* __restrict__ a_i, const float* __restrict__ a_jn,
        int* __restrict__ cursor, uint4* __restrict__ rec, int E){
    __shared__ float CK[12];
    if (threadIdx.x < 12) CK[threadIdx.x] = consts[threadIdx.x];
    __syncthreads();
    int eA = (blockIdx.x*256 + threadIdx.x)*2;
    int eB = eA + 1;
    bool vA = eA < E, vB = eB < E;
    int cA = vA ? eA : 0, cB = vB ? eB : 0;
    int sA = ei[cA], dA = ei[E + cA];
    int sB = ei[cB], dB = ei[E + cB];
    int posA = vA ? atomicAdd(cursor + sA, 1) : 0;
    int posB = vB ? atomicAdd(cursor + sB, 1) : 0;
    float eaA[NUM_BOND], eaB[NUM_BOND];
    #pragma unroll
    for (int b = 0; b < NUM_BOND; b++) eaA[b] = edge_attr[(size_t)cA*NUM_BOND + b];
    #pragma unroll
    for (int b = 0; b < NUM_BOND; b++) eaB[b] = edge_attr[(size_t)cB*NUM_BOND + b];
    float2 aiA = *(const float2*)(a_i + (size_t)sA*2);
    float2 aiB = *(const float2*)(a_i + (size_t)sB*2);
    float2 ajA = *(const float2*)(a_jn + (size_t)dA*2);
    float2 ajB = *(const float2*)(a_jn + (size_t)dB*2);
    float ajeA0 = CK[10], ajeA1 = CK[11], ajeB0 = CK[10], ajeB1 = CK[11];
    #pragma unroll
    for (int b = 0; b < NUM_BOND; b++){
        ajeA0 += eaA[b] * CK[2*b]; ajeA1 += eaA[b] * CK[2*b + 1];
        ajeB0 += eaB[b] * CK[2*b]; ajeB1 += eaB[b] * CK[2*b + 1];
    }
    float tA0 = aiA.x + ajA.x + ajeA0, tA1 = aiA.y + ajA.y + ajeA1;
    float tB0 = aiB.x + ajB.x + ajeB0, tB1 = aiB.y + ajB.y + ajeB1;
    float exA0 = __expf(fmaxf(tA0, NEG_SLOPE*tA0));
    float exA1 = __expf(fmaxf(tA1, NEG_SLOPE*tA1));
    float exB0 = __expf(fmaxf(tB0, NEG_SLOPE*tB0));
    float exB1 = __expf(fmaxf(tB1, NEG_SLOPE*tB1));
    if (vA){
        rec[posA] = make_uint4((unsigned)dA | (bf16rne(eaA[4]) << 16),
                               bf16rne(exA0) | (bf16rne(exA1) << 16),
                               bf16rne(eaA[0]) | (bf16rne(eaA[1]) << 16),
                               bf16rne(eaA[2]) | (bf16rne(eaA[3]) << 16));
    }
    if (vB){
        rec[posB] = make_uint4((unsigned)dB | (bf16rne(eaB[4]) << 16),
                               bf16rne(exB0) | (bf16rne(exB1) << 16),
                               bf16rne(eaB[0]) | (bf16rne(eaB[1]) << 16),
                               bf16rne(eaB[2]) | (bf16rne(eaB[3]) << 16));
    }
}

// FOUR nodes per wave: each quarter-wave (16 lanes) walks one node's CSR list.
// Lane l covers channels 4l..4l+3 via one uint4 hb load (256 B/row coalesced).
// Branch-free clamped 1-ahead prefetch; pure-FMA inner loop.
__global__ __launch_bounds__(256, 8) void k_gat(const uint4* __restrict__ rec,
        const int* __restrict__ offsets, const int* __restrict__ cnt,
        const unsigned* __restrict__ hb,
        const float* __restrict__ W_edge, const float* __restrict__ b_edge,
        const float* __restrict__ bias, float* __restrict__ out, int N){
    __shared__ float WE[NUM_BOND*128];
    __shared__ float BE[128];
    int t = threadIdx.x;
    for (int i = t; i < NUM_BOND*128; i += 256) WE[i] = W_edge[i];
    if (t < 128) BE[t] = b_edge[t];
    __syncthreads();
    int n = blockIdx.x*16 + (t >> 4);    // 16 quarter-waves per block
    int l = t & 15;                      // channels 4l..4l+3
    if (n >= N) return;

    int start = offsets[n], deg = cnt[n];

    float d0=0.f, d1=0.f;
    float A00=0.f, A01=0.f, A02=0.f, A03=0.f;   // head0, 4 channels
    float A10=0.f, A11=0.f, A12=0.f, A13=0.f;   // head1
    float eb00=0.f, eb01=0.f, eb02=0.f, eb03=0.f, eb04=0.f;
    float eb10=0.f, eb11=0.f, eb12=0.f, eb13=0.f, eb14=0.f;

    uint4 rN = make_uint4(0,0,0,0);
    uint4 hvN = make_uint4(0,0,0,0);
    if (deg > 0){
        rN  = rec[start];
        hvN = *(const uint4*)(hb + (size_t)(rN.x & 0xFFFFu)*EMB + 4*l);
    }
    for (int k = 0; k < deg; k++){
        uint4 r = rN; uint4 hv = hvN;
        int kn = (k + 1 < deg) ? (k + 1) : k;      // clamped, branch-free
        rN  = rec[start + kn];
        hvN = *(const uint4*)(hb + (size_t)(rN.x & 0xFFFFu)*EMB + 4*l);
        float e0 = bf16lo(r.y), e1 = bf16hi(r.y);
        float ea0 = bf16lo(r.z), ea1 = bf16hi(r.z);
        float ea2 = bf16lo(r.w), ea3 = bf16hi(r.w);
        float ea4 = bf16hi(r.x);
        float h00 = bf16lo(hv.x), h10 = bf16hi(hv.x);
        float h01 = bf16lo(hv.y), h11 = bf16hi(hv.y);
        float h02 = bf16lo(hv.z), h12 = bf16hi(hv.z);
        float h03 = bf16lo(hv.w), h13 = bf16hi(hv.w);
        d0 += e0; d1 += e1;
        A00 = fmaf(e0, h00, A00); A01 = fmaf(e0, h01, A01);
        A02 = fmaf(e0, h02, A02); A03 = fmaf(e0, h03, A03);
        A10 = fmaf(e1, h10, A10); A11 = fmaf(e1, h11, A11);
        A12 = fmaf(e1, h12, A12); A13 = fmaf(e1, h13, A13);
        eb00 = fmaf(e0, ea0, eb00); eb01 = fmaf(e0, ea1, eb01);
        eb02 = fmaf(e0, ea2, eb02); eb03 = fmaf(e0, ea3, eb03);
        eb04 = fmaf(e0, ea4, eb04);
        eb10 = fmaf(e1, ea0, eb10); eb11 = fmaf(e1, ea1, eb11);
        eb12 = fmaf(e1, ea2, eb12); eb13 = fmaf(e1, ea3, eb13);
        eb14 = fmaf(e1, ea4, eb14);
    }
    int c = 4*l;
    float id0 = 1.f/(d0 + 1e-16f), id1 = 1.f/(d1 + 1e-16f);
    float4 res;
    float* rp = (float*)&res;
    #pragma unroll
    for (int j = 0; j < 4; j++){
        int cj = c + j;
        float Aj0 = (j==0)?A00:(j==1)?A01:(j==2)?A02:A03;
        float Aj1 = (j==0)?A10:(j==1)?A11:(j==2)?A12:A13;
        float num0 = fmaf(d0, BE[cj], Aj0);
        float num1 = fmaf(d1, BE[64 + cj], Aj1);
        num0 = fmaf(eb00, WE[cj],       num0);
        num0 = fmaf(eb01, WE[128 + cj], num0);
        num0 = fmaf(eb02, WE[256 + cj], num0);
        num0 = fmaf(eb03, WE[384 + cj], num0);
        num0 = fmaf(eb04, WE[512 + cj], num0);
        num1 = fmaf(eb10, WE[64 + cj],  num1);
        num1 = fmaf(eb11, WE[192 + cj], num1);
        num1 = fmaf(eb12, WE[320 + cj], num1);
        num1 = fmaf(eb13, WE[448 + cj], num1);
        num1 = fmaf(eb14, WE[576 + cj], num1);
        rp[j] = 0.5f*(num0*id0 + num1*id1) + bias[cj];
    }
    *(float4*)(out + (size_t)n*EMB + c) = res;
}

extern "C" void kernel_launch(void* const* d_in, const int* in_sizes, int n_in,
                              void* d_out, int out_size, void* d_ws, size_t ws_size,
                              hipStream_t stream){
    const float* x         = (const float*)d_in[0];
    const int*   ei        = (const int*)d_in[1];      // int32 [2][E]
    const float* edge_attr = (const float*)d_in[2];
    const float* W_lin     = (const float*)d_in[3];
    const float* b_lin     = (const float*)d_in[4];
    const float* W_edge    = (const float*)d_in[5];
    const float* b_edge    = (const float*)d_in[6];
    const float* att       = (const float*)d_in[7];
    const float* bias      = (const float*)d_in[8];
    int N = in_sizes[0] / EMB;          // 50000 (< 65536: dst packs into u16)
    int E = in_sizes[2] / NUM_BOND;
    int nb = (N + 1023) >> 10;

    float* ws     = (float*)d_ws;
    unsigned* hb  = (unsigned*)ws;                     // N*64 packed bf16x2
    float* a_i    = (float*)(hb + (size_t)N*EMB);      // N*2
    float* a_jn   = a_i + (size_t)N*2;                 // N*2
    float* watt   = a_jn + (size_t)N*2;                // 256
    float* bconst = watt + 256;                        // 4
    float* consts = bconst + 4;                        // 12
    int*   cnt    = (int*)(consts + 12);               // N
    int*   loc    = cnt + N;                           // N
    int*   bsum   = loc + N;                           // 64
    int*   offsets= bsum + 64;                         // N
    int*   cursor = offsets + N;                       // N
    uintptr_t raddr = (uintptr_t)(cursor + N);
    raddr = (raddr + 15) & ~(uintptr_t)15;
    uint4* rec    = (uint4*)raddr;                     // E * 16 B

    hipMemsetAsync(cnt, 0, (size_t)N*sizeof(int), stream);

    k_setup  <<<1, 256, 0, stream>>>(W_lin, b_lin, W_edge, b_edge, att,
                                     watt, bconst, consts);
    k_node   <<<(N + 31)/32, 256, 0, stream>>>(x, W_lin, b_lin, watt, bconst,
                                               ei, E, hb, a_i, a_jn, cnt, N);
    k_scan1  <<<nb, 1024, 0, stream>>>(cnt, loc, bsum, N);
    k_scan2  <<<1, 64, 0, stream>>>(bsum, nb);
    k_scan3  <<<nb, 1024, 0, stream>>>(loc, bsum, offsets, cursor, N);
    k_scatter<<<(E + 511)/512, 256, 0, stream>>>(ei, edge_attr, consts, a_i, a_jn,
                                                 cursor, rec, E);
    k_gat    <<<(N + 15)/16, 256, 0, stream>>>(rec, offsets, cnt, hb,
                                               W_edge, b_edge, bias, (float*)d_out, N);
}